// Round 2
// baseline (85.484 us; speedup 1.0000x reference)
//
#include <hip/hip_runtime.h>
#include <cstdint>
#include <cmath>

#define N_WIRES 10
#define DIM 1024          // 2^N_WIRES amplitudes
#define BLK 256
#define N_OPS 30

struct GateSpec { int type[N_OPS]; int w0[N_OPS]; int w1[N_OPS]; };
// type: 0=rx, 1=ry, 2=rz, 3=cnot

// ---------------- host-side numpy RandomState(42) replication ----------------
namespace {

struct MT19937 {
  uint32_t mt[624];
  int mti;
  explicit MT19937(uint32_t s) {
    mt[0] = s;
    for (int i = 1; i < 624; ++i)
      mt[i] = 1812433253u * (mt[i - 1] ^ (mt[i - 1] >> 30)) + (uint32_t)i;
    mti = 624;
  }
  uint32_t next32() {
    if (mti >= 624) {
      for (int i = 0; i < 624; ++i) {
        uint32_t y = (mt[i] & 0x80000000u) | (mt[(i + 1) % 624] & 0x7fffffffu);
        uint32_t v = mt[(i + 397) % 624] ^ (y >> 1);
        if (y & 1u) v ^= 2567483615u;  // 0x9908b0df
        mt[i] = v;
      }
      mti = 0;
    }
    uint32_t y = mt[mti++];
    y ^= y >> 11;
    y ^= (y << 7) & 2636928640u;   // 0x9d2c5680
    y ^= (y << 15) & 4022730752u;  // 0xefc60000
    y ^= y >> 18;
    return y;
  }
  // Legacy randomkit bounded draw, range [0, rng] inclusive.
  // CRITICAL: for rng < 2^32 the legacy stream uses a SINGLE 32-bit draw
  // (rk_random_uint64's 32-bit fast path / legacy_random_bounded_uint64),
  // regardless of the requested int64 dtype. Same function serves
  // shuffle's random_interval.
  uint32_t masked32(uint32_t rng) {
    if (rng == 0) return 0;
    uint32_t mask = rng;
    mask |= mask >> 1; mask |= mask >> 2; mask |= mask >> 4;
    mask |= mask >> 8; mask |= mask >> 16;
    uint32_t v;
    do { v = next32() & mask; } while (v > rng);
    return v;
  }
};

void build_spec(GateSpec& spec) {
  MT19937 mt(42u);
  for (int k = 0; k < N_OPS; ++k) {
    int g = (int)mt.masked32(3);  // randint(4): one 32-bit draw, mask=3
    if (g == 3) {                 // 'cnot': choice(10, 2, replace=False) = permutation(10)[:2]
      int arr[N_WIRES];
      for (int i = 0; i < N_WIRES; ++i) arr[i] = i;
      for (int i = N_WIRES - 1; i >= 1; --i) {  // Fisher-Yates, i = 9..1
        int j = (int)mt.masked32((uint32_t)i);  // random_interval(i), 32-bit path
        int tmp = arr[i]; arr[i] = arr[j]; arr[j] = tmp;
      }
      spec.type[k] = 3; spec.w0[k] = arr[0]; spec.w1[k] = arr[1];
    } else {
      spec.type[k] = g;
      spec.w0[k] = (int)mt.masked32(9);  // randint(10): one 32-bit draw, mask=15
      spec.w1[k] = -1;
    }
  }
}

}  // namespace

// --------------------------------- device ------------------------------------

__global__ __launch_bounds__(BLK)
void qsim_kernel(const float* __restrict__ xb,   // (bsz, 10)
                 const float* __restrict__ rxt,  // (1,)
                 const float* __restrict__ ryt,  // (1,)
                 const float* __restrict__ rp,   // (30,)
                 const float* __restrict__ hw,   // (1, 10)
                 const float* __restrict__ hb,   // (1,)
                 float* __restrict__ out,        // (bsz,)
                 GateSpec spec) {
  const int b = blockIdx.x;
  const int tid = threadIdx.x;

  __shared__ float sre[DIM];
  __shared__ float sim[DIM];
  __shared__ float gc[42];  // cos(t/2): [0..9]=encoder, [10..39]=rand, [40]=rx, [41]=ry
  __shared__ float gs[42];  // sin(t/2)
  __shared__ float wsum[BLK / 64];

  if (tid < 42) {
    float t;
    if (tid < N_WIRES)               t = xb[(size_t)b * N_WIRES + tid];
    else if (tid < N_WIRES + N_OPS)  t = rp[tid - N_WIRES];
    else if (tid == 40)              t = rxt[0];
    else                             t = ryt[0];
    float s, c;
    sincosf(0.5f * t, &s, &c);
    gs[tid] = s; gc[tid] = c;
  }
  __syncthreads();

  // ---- encoder: RY(x_w) on each wire of |0..0> => real product state ----
  float cw[N_WIRES], sw[N_WIRES];
  #pragma unroll
  for (int w = 0; w < N_WIRES; ++w) { cw[w] = gc[w]; sw[w] = gs[w]; }
  #pragma unroll
  for (int r = 0; r < DIM / BLK; ++r) {
    int idx = tid + r * BLK;
    float a = 1.0f;
    #pragma unroll
    for (int w = 0; w < N_WIRES; ++w)
      a *= ((idx >> (N_WIRES - 1 - w)) & 1) ? sw[w] : cw[w];  // wire w = bit (9-w)
    sre[idx] = a;
    sim[idx] = 0.0f;
  }

  // ---- generic 1-qubit complex 2x2 gate on wire w ----
  auto apply1q = [&](int w, float u00r, float u00i, float u01r, float u01i,
                     float u10r, float u10i, float u11r, float u11i) {
    const int p = N_WIRES - 1 - w;
    const int pm = (1 << p) - 1;
    __syncthreads();
    #pragma unroll
    for (int r = 0; r < 2; ++r) {
      int t = tid + r * BLK;            // 0..511 pairs, disjoint ownership
      int lo = t & pm;
      int i0 = ((t ^ lo) << 1) | lo;    // ((t>>p)<<(p+1)) | lo
      int i1 = i0 | (1 << p);
      float a0r = sre[i0], a0i = sim[i0];
      float a1r = sre[i1], a1i = sim[i1];
      sre[i0] = u00r * a0r - u00i * a0i + u01r * a1r - u01i * a1i;
      sim[i0] = u00r * a0i + u00i * a0r + u01r * a1i + u01i * a1r;
      sre[i1] = u10r * a0r - u10i * a0i + u11r * a1r - u11i * a1i;
      sim[i1] = u10r * a0i + u10i * a0r + u11r * a1i + u11i * a1r;
    }
  };

  // ---- random layer (fixed 30-gate spec, batch-uniform angles) ----
  for (int k = 0; k < N_OPS; ++k) {
    const int ty = spec.type[k];
    if (ty == 3) {
      const int pc = N_WIRES - 1 - spec.w0[k];
      const int pt = N_WIRES - 1 - spec.w1[k];
      const int pl = pc < pt ? pc : pt;
      const int ph = pc < pt ? pt : pc;
      __syncthreads();
      int i = tid;  // 256 pairs: 8 free bits
      i = ((i >> pl) << (pl + 1)) | (i & ((1 << pl) - 1));
      i = ((i >> ph) << (ph + 1)) | (i & ((1 << ph) - 1));
      const int i0 = i | (1 << pc);       // control=1, target=0
      const int i1 = i0 | (1 << pt);      // control=1, target=1
      float tr = sre[i0], ti = sim[i0];
      sre[i0] = sre[i1]; sim[i0] = sim[i1];
      sre[i1] = tr;      sim[i1] = ti;
    } else {
      const float c = gc[N_WIRES + k], s = gs[N_WIRES + k];
      if (ty == 0)       apply1q(spec.w0[k], c, 0.f,  0.f, -s,   0.f, -s,   c, 0.f);  // rx
      else if (ty == 1)  apply1q(spec.w0[k], c, 0.f,  -s,  0.f,  s,   0.f,  c, 0.f);  // ry
      else               apply1q(spec.w0[k], c, -s,   0.f, 0.f,  0.f, 0.f,  c, s);    // rz
    }
  }

  // ---- shared trainable RX then RY on every wire ----
  {
    const float cx = gc[40], sx = gs[40];
    const float cy = gc[41], sy = gs[41];
    for (int w = 0; w < N_WIRES; ++w) {
      apply1q(w, cx, 0.f, 0.f, -sx, 0.f, -sx, cx, 0.f);   // RX
      apply1q(w, cy, 0.f, -sy, 0.f, sy,  0.f, cy, 0.f);   // RY
    }
  }

  __syncthreads();

  // ---- MeasureAll(Z) folded into head: logit = sum_idx pr[idx]*wgt[idx] ----
  float hwr[N_WIRES];
  #pragma unroll
  for (int w = 0; w < N_WIRES; ++w) hwr[w] = hw[w];
  float partial = 0.0f;
  #pragma unroll
  for (int r = 0; r < DIM / BLK; ++r) {
    int idx = tid + r * BLK;
    float re = sre[idx], im = sim[idx];
    float pr = re * re + im * im;
    float wgt = 0.0f;
    #pragma unroll
    for (int w = 0; w < N_WIRES; ++w)
      wgt += ((idx >> (N_WIRES - 1 - w)) & 1) ? -hwr[w] : hwr[w];
    partial += pr * wgt;
  }
  #pragma unroll
  for (int off = 32; off > 0; off >>= 1)
    partial += __shfl_down(partial, off, 64);
  if ((tid & 63) == 0) wsum[tid >> 6] = partial;
  __syncthreads();
  if (tid == 0) {
    float logit = wsum[0] + wsum[1] + wsum[2] + wsum[3] + hb[0]
                + 1.57079632679489662f;  // + SHIFT
    out[b] = 1.0f / (1.0f + expf(-logit));
  }
}

// ---------------------------------- launch -----------------------------------

extern "C" void kernel_launch(void* const* d_in, const int* in_sizes, int n_in,
                              void* d_out, int out_size, void* d_ws, size_t ws_size,
                              hipStream_t stream) {
  const float* xb  = (const float*)d_in[0];  // state_batch (bsz,10)
  const float* rxt = (const float*)d_in[1];  // rx_theta (1,)
  const float* ryt = (const float*)d_in[2];  // ry_theta (1,)
  const float* rp  = (const float*)d_in[3];  // rand_params (30,)
  const float* hw  = (const float*)d_in[4];  // head_w (1,10)
  const float* hb  = (const float*)d_in[5];  // head_b (1,)
  float* out = (float*)d_out;

  const int bsz = in_sizes[0] / N_WIRES;

  GateSpec spec;
  build_spec(spec);  // pure host compute, deterministic, capture-safe

  hipLaunchKernelGGL(qsim_kernel, dim3(bsz), dim3(BLK), 0, stream,
                     xb, rxt, ryt, rp, hw, hb, out, spec);
}

// Round 3
// 44.931 us; speedup vs baseline: 1.9026x; 1.9026x over previous
//
#include <hip/hip_runtime.h>
#include <cstdint>
#include <cmath>

#define N_WIRES 10
#define N_OPS 30
#define N_TOTAL 50   // 30 random + 10x(RX,RY) shared

// ---------------- compile-time numpy RandomState(42) replication -------------
// Gate spec is fully deterministic => evaluate the MT19937 at COMPILE TIME and
// unroll the whole circuit with static wires (register-resident state needs
// static indexing; rule #20).

struct Spec { int type[N_TOTAL]; int p0[N_TOTAL]; int p1[N_TOTAL]; int aidx[N_TOTAL]; };
// type: 0=rx 1=ry 2=rz 3=cnot.  p0/p1 are BIT positions (bit = 9 - wire).
// aidx: source lane of the (cos,sin) angle pair (lane table below).

struct CERng { uint32_t mt[624]; int mti; };

constexpr uint32_t ce_next32(CERng& r) {
  if (r.mti >= 624) {
    for (int i = 0; i < 624; ++i) {
      uint32_t y = (r.mt[i] & 0x80000000u) | (r.mt[(i + 1) % 624] & 0x7fffffffu);
      uint32_t v = r.mt[(i + 397) % 624] ^ (y >> 1);
      if (y & 1u) v ^= 2567483615u;  // 0x9908b0df
      r.mt[i] = v;
    }
    r.mti = 0;
  }
  uint32_t y = r.mt[r.mti++];
  y ^= y >> 11;
  y ^= (y << 7) & 2636928640u;
  y ^= (y << 15) & 4022730752u;
  y ^= y >> 18;
  return y;
}

// Legacy randomkit bounded draw: single 32-bit masked-rejection (validated R2).
constexpr uint32_t ce_masked(CERng& r, uint32_t rng) {
  if (rng == 0) return 0;
  uint32_t mask = rng;
  mask |= mask >> 1; mask |= mask >> 2; mask |= mask >> 4;
  mask |= mask >> 8; mask |= mask >> 16;
  uint32_t v = ce_next32(r) & mask;
  while (v > rng) v = ce_next32(r) & mask;
  return v;
}

constexpr Spec make_spec() {
  Spec sp{};
  CERng r{};
  r.mt[0] = 42u;
  for (int i = 1; i < 624; ++i)
    r.mt[i] = 1812433253u * (r.mt[i - 1] ^ (r.mt[i - 1] >> 30)) + (uint32_t)i;
  r.mti = 624;
  for (int k = 0; k < N_OPS; ++k) {
    int g = (int)ce_masked(r, 3u);
    if (g == 3) {  // cnot: permutation(10)[:2] via Fisher-Yates
      int arr[N_WIRES] = {0, 1, 2, 3, 4, 5, 6, 7, 8, 9};
      for (int i = N_WIRES - 1; i >= 1; --i) {
        int j = (int)ce_masked(r, (uint32_t)i);
        int t = arr[i]; arr[i] = arr[j]; arr[j] = t;
      }
      sp.type[k] = 3; sp.p0[k] = 9 - arr[0]; sp.p1[k] = 9 - arr[1]; sp.aidx[k] = 0;
    } else {
      sp.type[k] = g; sp.p0[k] = 9 - (int)ce_masked(r, 9u); sp.p1[k] = 0;
      sp.aidx[k] = 10 + k;
    }
  }
  for (int w = 0; w < N_WIRES; ++w) {  // shared RX then RY on every wire
    sp.type[30 + 2 * w] = 0; sp.p0[30 + 2 * w] = 9 - w; sp.p1[30 + 2 * w] = 0; sp.aidx[30 + 2 * w] = 40;
    sp.type[31 + 2 * w] = 1; sp.p0[31 + 2 * w] = 9 - w; sp.p1[31 + 2 * w] = 0; sp.aidx[31 + 2 * w] = 41;
  }
  return sp;
}

constexpr Spec SPEC = make_spec();

// --------------------------------- device ------------------------------------
// State layout: global index = (lane << 4) | slot.  Bits 0..3 = slot (register),
// bits 4..9 = lane.  re[16]/im[16] live in VGPRs; all indexing static.

template <int TY, int P>
__device__ inline void gate_local(float (&re)[16], float (&im)[16], float c, float s) {
  #pragma unroll
  for (int b = 0; b < 16; ++b) {
    if ((b >> P) & 1) continue;           // compile-time
    const int i0 = b, i1 = b | (1 << P);
    const float r0 = re[i0], m0 = im[i0], r1 = re[i1], m1 = im[i1];
    if constexpr (TY == 0) {              // RX: out = c*self - i*s*other
      re[i0] = c * r0 + s * m1; im[i0] = c * m0 - s * r1;
      re[i1] = c * r1 + s * m0; im[i1] = c * m1 - s * r0;
    } else if constexpr (TY == 1) {       // RY
      re[i0] = c * r0 - s * r1; im[i0] = c * m0 - s * m1;
      re[i1] = c * r1 + s * r0; im[i1] = c * m1 + s * m0;
    } else {                              // RZ (diagonal)
      re[i0] = c * r0 + s * m0; im[i0] = c * m0 - s * r0;
      re[i1] = c * r1 - s * m1; im[i1] = c * m1 + s * r1;
    }
  }
}

template <int TY, int LB>
__device__ inline void gate_lane(float (&re)[16], float (&im)[16], float c, float s, int lane) {
  if constexpr (TY == 2) {                // RZ: no exchange needed
    const float t = ((lane >> LB) & 1) ? -s : s;
    #pragma unroll
    for (int j = 0; j < 16; ++j) {
      const float r = re[j], m = im[j];
      re[j] = c * r + t * m; im[j] = c * m - t * r;
    }
  } else if constexpr (TY == 0) {         // RX: out = c*self - i*s*partner (both bits)
    #pragma unroll
    for (int j = 0; j < 16; ++j) {
      const float rp = __shfl_xor(re[j], 1 << LB, 64);
      const float mp = __shfl_xor(im[j], 1 << LB, 64);
      const float r = re[j], m = im[j];
      re[j] = c * r + s * mp; im[j] = c * m - s * rp;
    }
  } else {                                // RY: out = c*self +/- s*partner
    const float sg = ((lane >> LB) & 1) ? s : -s;
    #pragma unroll
    for (int j = 0; j < 16; ++j) {
      const float rp = __shfl_xor(re[j], 1 << LB, 64);
      const float mp = __shfl_xor(im[j], 1 << LB, 64);
      re[j] = c * re[j] + sg * rp; im[j] = c * im[j] + sg * mp;
    }
  }
}

template <int CB, int TB>
__device__ inline void cnot_gate(float (&re)[16], float (&im)[16], int lane) {
  if constexpr (CB < 4 && TB < 4) {       // both register bits: static swap
    #pragma unroll
    for (int b = 0; b < 16; ++b) {
      if (((b >> CB) & 1) && !((b >> TB) & 1)) {
        const int j = b | (1 << TB);
        float t = re[b]; re[b] = re[j]; re[j] = t;
        t = im[b]; im[b] = im[j]; im[j] = t;
      }
    }
  } else if constexpr (CB < 4) {          // control register, target lane: exchange
    constexpr int TM = 1 << (TB - 4);
    #pragma unroll
    for (int b = 0; b < 16; ++b) {
      if ((b >> CB) & 1) {                // compile-time; all lanes execute shfl
        re[b] = __shfl_xor(re[b], TM, 64);
        im[b] = __shfl_xor(im[b], TM, 64);
      }
    }
  } else if constexpr (TB < 4) {          // control lane, target register: cndmask swap
    const bool cb = (lane >> (CB - 4)) & 1;
    #pragma unroll
    for (int b = 0; b < 16; ++b) {
      if (!((b >> TB) & 1)) {
        const int j = b | (1 << TB);
        const float r0 = re[b], r1 = re[j], m0 = im[b], m1 = im[j];
        re[b] = cb ? r1 : r0; re[j] = cb ? r0 : r1;
        im[b] = cb ? m1 : m0; im[j] = cb ? m0 : m1;
      }
    }
  } else {                                // both lane bits
    const bool cb = (lane >> (CB - 4)) & 1;
    constexpr int TM = 1 << (TB - 4);
    #pragma unroll
    for (int j = 0; j < 16; ++j) {
      const float rp = __shfl_xor(re[j], TM, 64);
      const float mp = __shfl_xor(im[j], TM, 64);
      re[j] = cb ? rp : re[j];
      im[j] = cb ? mp : im[j];
    }
  }
}

template <int K>
__device__ inline void run_gates(float (&re)[16], float (&im)[16],
                                 float tc, float ts, int lane) {
  if constexpr (K < N_TOTAL) {
    constexpr int ty = SPEC.type[K];
    if constexpr (ty == 3) {
      cnot_gate<SPEC.p0[K], SPEC.p1[K]>(re, im, lane);
    } else {
      const float c = __shfl(tc, SPEC.aidx[K], 64);
      const float s = __shfl(ts, SPEC.aidx[K], 64);
      constexpr int P = SPEC.p0[K];
      if constexpr (P < 4) gate_local<ty, P>(re, im, c, s);
      else                 gate_lane<ty, P - 4>(re, im, c, s, lane);
    }
    run_gates<K + 1>(re, im, tc, ts, lane);
  }
}

__global__ __launch_bounds__(256)
void qsim_kernel(const float* __restrict__ xb,   // (bsz, 10)
                 const float* __restrict__ rxt,  // (1,)
                 const float* __restrict__ ryt,  // (1,)
                 const float* __restrict__ rp,   // (30,)
                 const float* __restrict__ hw,   // (1, 10)
                 const float* __restrict__ hb,   // (1,)
                 float* __restrict__ out,        // (bsz,)
                 int bsz) {
  const int lane = threadIdx.x & 63;
  const int b = blockIdx.x * 4 + (threadIdx.x >> 6);  // one wave = one sample
  if (b >= bsz) return;

  // Angle table, one (c,s) pair per lane:
  //   lanes 0..9  : this sample's encoder RY angles
  //   lanes 10..39: rand_params, lane 40: rx_theta, lane 41: ry_theta
  float tc, ts;
  {
    float t = 0.0f;
    if (lane < 10)        t = xb[(size_t)b * 10 + lane];
    else if (lane < 40)   t = rp[lane - 10];
    else if (lane == 40)  t = rxt[0];
    else if (lane == 41)  t = ryt[0];
    float s, c;
    sincosf(0.5f * t, &s, &c);
    tc = c; ts = s;
  }

  // ---- encoder: product state.  bit(9-w) set => sin(x_w/2) else cos ----
  float ec[N_WIRES], es[N_WIRES];
  #pragma unroll
  for (int w = 0; w < N_WIRES; ++w) { ec[w] = __shfl(tc, w, 64); es[w] = __shfl(ts, w, 64); }
  float lp = 1.0f;
  #pragma unroll
  for (int w = 0; w < 6; ++w)                    // lane bit (5-w) <-> wire w
    lp *= ((lane >> (5 - w)) & 1) ? es[w] : ec[w];
  float re[16], im[16];
  #pragma unroll
  for (int sl = 0; sl < 16; ++sl) {
    float a = lp;
    #pragma unroll
    for (int w = 6; w < N_WIRES; ++w)            // slot bit (9-w) <-> wire w
      a *= ((sl >> (9 - w)) & 1) ? es[w] : ec[w];
    re[sl] = a; im[sl] = 0.0f;
  }

  // ---- 50 gates, fully unrolled at compile time ----
  run_gates<0>(re, im, tc, ts, lane);

  // ---- MeasureAll(Z) folded into linear head ----
  float hwv[N_WIRES];
  #pragma unroll
  for (int w = 0; w < N_WIRES; ++w) hwv[w] = hw[w];
  float lw = 0.0f;
  #pragma unroll
  for (int w = 0; w < 6; ++w)
    lw += ((lane >> (5 - w)) & 1) ? -hwv[w] : hwv[w];
  float acc = 0.0f;
  #pragma unroll
  for (int sl = 0; sl < 16; ++sl) {
    float sw = lw;
    #pragma unroll
    for (int w = 6; w < N_WIRES; ++w)
      sw += ((sl >> (9 - w)) & 1) ? -hwv[w] : hwv[w];
    acc += (re[sl] * re[sl] + im[sl] * im[sl]) * sw;
  }
  #pragma unroll
  for (int off = 32; off; off >>= 1) acc += __shfl_xor(acc, off, 64);
  if (lane == 0) {
    const float logit = acc + hb[0] + 1.57079632679489662f;  // + SHIFT
    out[b] = 1.0f / (1.0f + expf(-logit));
  }
}

// ---------------------------------- launch -----------------------------------

extern "C" void kernel_launch(void* const* d_in, const int* in_sizes, int n_in,
                              void* d_out, int out_size, void* d_ws, size_t ws_size,
                              hipStream_t stream) {
  const float* xb  = (const float*)d_in[0];
  const float* rxt = (const float*)d_in[1];
  const float* ryt = (const float*)d_in[2];
  const float* rp  = (const float*)d_in[3];
  const float* hw  = (const float*)d_in[4];
  const float* hb  = (const float*)d_in[5];
  float* out = (float*)d_out;

  const int bsz = in_sizes[0] / N_WIRES;
  const int nblk = (bsz + 3) / 4;   // 4 waves/block = 4 samples/block

  hipLaunchKernelGGL(qsim_kernel, dim3(nblk), dim3(256), 0, stream,
                     xb, rxt, ryt, rp, hw, hb, out, bsz);
}

// Round 5
// 33.379 us; speedup vs baseline: 2.5610x; 1.3461x over previous
//
#include <hip/hip_runtime.h>
#include <cstdint>
#include <cmath>

#define N_WIRES 10
#define N_OPS 30
#define NG_FAST 40   // 30 random + 10 fused(RY*RX)
#define NG_SAFE 50   // 30 random + 10x(RX,RY) separate (R3-proven tail)
#define NG_MAX 50

// ---------------- compile-time numpy RandomState(42) replication -------------

struct CERng { uint32_t mt[624]; int mti; };

constexpr uint32_t ce_next32(CERng& r) {
  if (r.mti >= 624) {
    for (int i = 0; i < 624; ++i) {
      uint32_t y = (r.mt[i] & 0x80000000u) | (r.mt[(i + 1) % 624] & 0x7fffffffu);
      uint32_t v = r.mt[(i + 397) % 624] ^ (y >> 1);
      if (y & 1u) v ^= 2567483615u;
      r.mt[i] = v;
    }
    r.mti = 0;
  }
  uint32_t y = r.mt[r.mti++];
  y ^= y >> 11;
  y ^= (y << 7) & 2636928640u;
  y ^= (y << 15) & 4022730752u;
  y ^= y >> 18;
  return y;
}

constexpr uint32_t ce_masked(CERng& r, uint32_t rng) {  // legacy single-32b draw (R2-validated)
  if (rng == 0) return 0;
  uint32_t mask = rng;
  mask |= mask >> 1; mask |= mask >> 2; mask |= mask >> 4;
  mask |= mask >> 8; mask |= mask >> 16;
  uint32_t v = ce_next32(r) & mask;
  while (v > rng) v = ce_next32(r) & mask;
  return v;
}

// type: 0=rx 1=ry 2=rz 3=cnot 4=fused(RY*RX).  p0/p1 are BIT positions after remap.
struct Full { int n; int type[NG_MAX]; int p0[NG_MAX]; int p1[NG_MAX]; int aidx[NG_MAX]; int wbit[N_WIRES]; };

constexpr Full make_full(bool fused) {
  Full f{};
  int rty[N_OPS] = {}, rw0[N_OPS] = {}, rw1[N_OPS] = {};
  CERng r{};
  r.mt[0] = 42u;
  for (int i = 1; i < 624; ++i)
    r.mt[i] = 1812433253u * (r.mt[i - 1] ^ (r.mt[i - 1] >> 30)) + (uint32_t)i;
  r.mti = 624;
  for (int k = 0; k < N_OPS; ++k) {
    int g = (int)ce_masked(r, 3u);
    if (g == 3) {
      int arr[N_WIRES] = {0,1,2,3,4,5,6,7,8,9};
      for (int i = N_WIRES - 1; i >= 1; --i) {
        int j = (int)ce_masked(r, (uint32_t)i);
        int t = arr[i]; arr[i] = arr[j]; arr[j] = t;
      }
      rty[k] = 3; rw0[k] = arr[0]; rw1[k] = arr[1];
    } else {
      rty[k] = g; rw0[k] = (int)ce_masked(r, 9u); rw1[k] = -1;
    }
  }
  // per-wire lane-exchange cost
  int cost[N_WIRES] = {};
  for (int k = 0; k < N_OPS; ++k) {
    if (rty[k] == 3) { cost[rw0[k]] += 1; cost[rw1[k]] += 2; }
    else if (rty[k] != 2) cost[rw0[k]] += 2;
  }
  for (int w = 0; w < N_WIRES; ++w) cost[w] += 2;
  int ord[N_WIRES] = {0,1,2,3,4,5,6,7,8,9};
  for (int i = 0; i < N_WIRES; ++i) {
    int best = i;
    for (int j = i + 1; j < N_WIRES; ++j)
      if (cost[ord[j]] > cost[ord[best]]) best = j;
    int t = ord[i]; ord[i] = ord[best]; ord[best] = t;
  }
  // hottest 4 -> register bits; lane bits by mechanism cost:
  // bit4/5 = DPP(mask1/2), bit8/9 = permlane(mask16/32), bit6/7 = ds_swizzle(mask4/8)
  f.wbit[ord[0]] = 3; f.wbit[ord[1]] = 2; f.wbit[ord[2]] = 1; f.wbit[ord[3]] = 0;
  f.wbit[ord[4]] = 4; f.wbit[ord[5]] = 5;
  f.wbit[ord[6]] = 8; f.wbit[ord[7]] = 9;
  f.wbit[ord[8]] = 6; f.wbit[ord[9]] = 7;
  for (int k = 0; k < N_OPS; ++k) {
    f.type[k] = rty[k];
    if (rty[k] == 3) { f.p0[k] = f.wbit[rw0[k]]; f.p1[k] = f.wbit[rw1[k]]; f.aidx[k] = 0; }
    else             { f.p0[k] = f.wbit[rw0[k]]; f.p1[k] = 0; f.aidx[k] = 10 + k; }
  }
  if (fused) {
    f.n = NG_FAST;
    for (int w = 0; w < N_WIRES; ++w) {
      f.type[N_OPS + w] = 4; f.p0[N_OPS + w] = f.wbit[w]; f.p1[N_OPS + w] = 0; f.aidx[N_OPS + w] = 0;
    }
  } else {
    f.n = NG_SAFE;
    for (int w = 0; w < N_WIRES; ++w) {
      f.type[N_OPS + 2*w]     = 0; f.p0[N_OPS + 2*w]     = f.wbit[w]; f.p1[N_OPS + 2*w]     = 0; f.aidx[N_OPS + 2*w]     = 40;
      f.type[N_OPS + 2*w + 1] = 1; f.p0[N_OPS + 2*w + 1] = f.wbit[w]; f.p1[N_OPS + 2*w + 1] = 0; f.aidx[N_OPS + 2*w + 1] = 41;
    }
  }
  return f;
}

constexpr Full FULLF = make_full(true);
constexpr Full FULLS = make_full(false);

constexpr int wire_at_bit(int bp) {
  for (int w = 0; w < N_WIRES; ++w) if (FULLF.wbit[w] == bp) return w;
  return 0;
}
constexpr int RW0 = wire_at_bit(0), RW1 = wire_at_bit(1), RW2 = wire_at_bit(2), RW3 = wire_at_bit(3);
constexpr int LW0 = wire_at_bit(4), LW1 = wire_at_bit(5), LW2 = wire_at_bit(6),
              LW3 = wire_at_bit(7), LW4 = wire_at_bit(8), LW5 = wire_at_bit(9);

// --------------------------------- device ------------------------------------

struct U2 { float r00, i00, r01, i01, r10, i10, r11, i11; };
struct Ctx { int lane; bool f16, f32; };

template <bool SAFE>
__device__ inline float bcast(float x, int l) {
  if constexpr (SAFE) return __shfl(x, l, 64);
  else return __int_as_float(__builtin_amdgcn_readlane(__float_as_int(x), l));
}

// xor-exchange across lanes; SAFE => R3-proven __shfl_xor everywhere
template <int MASK, bool SAFE>
__device__ inline float xshfl(float x, const Ctx& cx) {
  if constexpr (SAFE) {
    return __shfl_xor(x, MASK, 64);
  } else if constexpr (MASK == 1) {        // quad_perm [1,0,3,2], pure VALU
    return __int_as_float(__builtin_amdgcn_update_dpp(0, __float_as_int(x), 0xB1, 0xF, 0xF, true));
  } else if constexpr (MASK == 2) {        // quad_perm [2,3,0,1]
    return __int_as_float(__builtin_amdgcn_update_dpp(0, __float_as_int(x), 0x4E, 0xF, 0xF, true));
  } else if constexpr (MASK == 4 || MASK == 8) {  // ds_swizzle xor-mode (DS pipe)
    return __int_as_float(__builtin_amdgcn_ds_swizzle(__float_as_int(x), (MASK << 10) | 0x1F));
  } else if constexpr (MASK == 16) {
#if __has_builtin(__builtin_amdgcn_permlane16_swap)
    auto r = __builtin_amdgcn_permlane16_swap(__float_as_int(x), __float_as_int(x), false, false);
    const int a = (cx.lane & 16) ? r[0] : r[1];
    const int b = (cx.lane & 16) ? r[1] : r[0];
    return __int_as_float(cx.f16 ? b : a);
#else
    return __shfl_xor(x, 16, 64);
#endif
  } else {  // MASK == 32
#if __has_builtin(__builtin_amdgcn_permlane32_swap)
    auto r = __builtin_amdgcn_permlane32_swap(__float_as_int(x), __float_as_int(x), false, false);
    const int a = (cx.lane & 32) ? r[0] : r[1];
    const int b = (cx.lane & 32) ? r[1] : r[0];
    return __int_as_float(cx.f32 ? b : a);
#else
    return __shfl_xor(x, 32, 64);
#endif
  }
}

template <int TY, int P>
__device__ inline void gate_local(float (&re)[16], float (&im)[16], float c, float s) {
  #pragma unroll
  for (int b = 0; b < 16; ++b) {
    if ((b >> P) & 1) continue;
    const int i0 = b, i1 = b | (1 << P);
    const float r0 = re[i0], m0 = im[i0], r1 = re[i1], m1 = im[i1];
    if constexpr (TY == 0) {              // RX
      re[i0] = c * r0 + s * m1; im[i0] = c * m0 - s * r1;
      re[i1] = c * r1 + s * m0; im[i1] = c * m1 - s * r0;
    } else if constexpr (TY == 1) {       // RY
      re[i0] = c * r0 - s * r1; im[i0] = c * m0 - s * m1;
      re[i1] = c * r1 + s * r0; im[i1] = c * m1 + s * m0;
    } else {                              // RZ
      re[i0] = c * r0 + s * m0; im[i0] = c * m0 - s * r0;
      re[i1] = c * r1 - s * m1; im[i1] = c * m1 + s * r1;
    }
  }
}

template <int TY, int LB, bool SAFE>
__device__ inline void gate_lane(float (&re)[16], float (&im)[16], float c, float s, const Ctx& cx) {
  if constexpr (TY == 2) {                // RZ: diagonal
    const float t = ((cx.lane >> LB) & 1) ? -s : s;
    #pragma unroll
    for (int j = 0; j < 16; ++j) {
      const float r = re[j], m = im[j];
      re[j] = c * r + t * m; im[j] = c * m - t * r;
    }
  } else if constexpr (TY == 0) {         // RX
    #pragma unroll
    for (int j = 0; j < 16; ++j) {
      const float rp = xshfl<(1 << LB), SAFE>(re[j], cx);
      const float mp = xshfl<(1 << LB), SAFE>(im[j], cx);
      const float r = re[j], m = im[j];
      re[j] = c * r + s * mp; im[j] = c * m - s * rp;
    }
  } else {                                // RY
    const float sg = ((cx.lane >> LB) & 1) ? s : -s;
    #pragma unroll
    for (int j = 0; j < 16; ++j) {
      const float rp = xshfl<(1 << LB), SAFE>(re[j], cx);
      const float mp = xshfl<(1 << LB), SAFE>(im[j], cx);
      re[j] = c * re[j] + sg * rp; im[j] = c * im[j] + sg * mp;
    }
  }
}

template <int P>
__device__ inline void fused_local(float (&re)[16], float (&im)[16], const U2& u) {
  #pragma unroll
  for (int b = 0; b < 16; ++b) {
    if ((b >> P) & 1) continue;
    const int i0 = b, i1 = b | (1 << P);
    const float r0 = re[i0], m0 = im[i0], r1 = re[i1], m1 = im[i1];
    re[i0] = u.r00 * r0 - u.i00 * m0 + u.r01 * r1 - u.i01 * m1;
    im[i0] = u.r00 * m0 + u.i00 * r0 + u.r01 * m1 + u.i01 * r1;
    re[i1] = u.r10 * r0 - u.i10 * m0 + u.r11 * r1 - u.i11 * m1;
    im[i1] = u.r10 * m0 + u.i10 * r0 + u.r11 * m1 + u.i11 * r1;
  }
}

template <int LB, bool SAFE>
__device__ inline void fused_lane(float (&re)[16], float (&im)[16], const U2& u, const Ctx& cx) {
  const bool hi = (cx.lane >> LB) & 1;
  const float Ar = hi ? u.r11 : u.r00, Ai = hi ? u.i11 : u.i00;
  const float Br = hi ? u.r10 : u.r01, Bi = hi ? u.i10 : u.i01;
  #pragma unroll
  for (int j = 0; j < 16; ++j) {
    const float rp = xshfl<(1 << LB), SAFE>(re[j], cx);
    const float mp = xshfl<(1 << LB), SAFE>(im[j], cx);
    const float r = re[j], m = im[j];
    re[j] = Ar * r - Ai * m + Br * rp - Bi * mp;
    im[j] = Ar * m + Ai * r + Br * mp + Bi * rp;
  }
}

template <int CB, int TB, bool SAFE>
__device__ inline void cnot_gate(float (&re)[16], float (&im)[16], const Ctx& cx) {
  if constexpr (CB < 4 && TB < 4) {
    #pragma unroll
    for (int b = 0; b < 16; ++b) {
      if (((b >> CB) & 1) && !((b >> TB) & 1)) {
        const int j = b | (1 << TB);
        float t = re[b]; re[b] = re[j]; re[j] = t;
        t = im[b]; im[b] = im[j]; im[j] = t;
      }
    }
  } else if constexpr (CB < 4) {
    constexpr int M = 1 << (TB - 4);
    #pragma unroll
    for (int b = 0; b < 16; ++b) {
      if ((b >> CB) & 1) { re[b] = xshfl<M, SAFE>(re[b], cx); im[b] = xshfl<M, SAFE>(im[b], cx); }
    }
  } else if constexpr (TB < 4) {
    const bool cb = (cx.lane >> (CB - 4)) & 1;
    #pragma unroll
    for (int b = 0; b < 16; ++b) {
      if (!((b >> TB) & 1)) {
        const int j = b | (1 << TB);
        const float r0 = re[b], r1 = re[j], m0 = im[b], m1 = im[j];
        re[b] = cb ? r1 : r0; re[j] = cb ? r0 : r1;
        im[b] = cb ? m1 : m0; im[j] = cb ? m0 : m1;
      }
    }
  } else {
    const bool cb = (cx.lane >> (CB - 4)) & 1;
    constexpr int M = 1 << (TB - 4);
    #pragma unroll
    for (int j = 0; j < 16; ++j) {
      const float rp = xshfl<M, SAFE>(re[j], cx);
      const float mp = xshfl<M, SAFE>(im[j], cx);
      re[j] = cb ? rp : re[j];
      im[j] = cb ? mp : im[j];
    }
  }
}

template <int K, bool SAFE>
__device__ inline void run_gates(float (&re)[16], float (&im)[16],
                                 float tc, float ts, const U2& u, const Ctx& cx) {
  constexpr int NG = SAFE ? NG_SAFE : NG_FAST;
  if constexpr (K < NG) {
    constexpr int ty = SAFE ? FULLS.type[K] : FULLF.type[K];
    constexpr int P0 = SAFE ? FULLS.p0[K]   : FULLF.p0[K];
    constexpr int P1 = SAFE ? FULLS.p1[K]   : FULLF.p1[K];
    constexpr int AI = SAFE ? FULLS.aidx[K] : FULLF.aidx[K];
    if constexpr (ty == 3) {
      cnot_gate<P0, P1, SAFE>(re, im, cx);
    } else if constexpr (ty == 4) {
      if constexpr (P0 < 4) fused_local<P0>(re, im, u);
      else                  fused_lane<P0 - 4, SAFE>(re, im, u, cx);
    } else {
      const float c = bcast<SAFE>(tc, AI);
      const float s = bcast<SAFE>(ts, AI);
      if constexpr (P0 < 4) gate_local<ty, P0>(re, im, c, s);
      else                  gate_lane<ty, P0 - 4, SAFE>(re, im, c, s, cx);
    }
    run_gates<K + 1, SAFE>(re, im, tc, ts, u, cx);
  }
}

template <bool SAFE>
__device__ inline void body(const Ctx& cx, int b, float tc, float ts,
                            const float* __restrict__ hw, const float* __restrict__ hb,
                            float* __restrict__ out) {
  const int lane = cx.lane;
  U2 u;
  {
    const float cxr = bcast<SAFE>(tc, 40), sxr = bcast<SAFE>(ts, 40);
    const float cyr = bcast<SAFE>(tc, 41), syr = bcast<SAFE>(ts, 41);
    u.r00 = cyr * cxr;  u.i00 = syr * sxr;
    u.r01 = -syr * cxr; u.i01 = -cyr * sxr;
    u.r10 = syr * cxr;  u.i10 = -cyr * sxr;
    u.r11 = cyr * cxr;  u.i11 = -syr * sxr;
  }
  float ec[N_WIRES], es[N_WIRES];
  #pragma unroll
  for (int w = 0; w < N_WIRES; ++w) { ec[w] = bcast<SAFE>(tc, w); es[w] = bcast<SAFE>(ts, w); }

  float lp = ((lane >> 0) & 1) ? es[LW0] : ec[LW0];
  lp *= ((lane >> 1) & 1) ? es[LW1] : ec[LW1];
  lp *= ((lane >> 2) & 1) ? es[LW2] : ec[LW2];
  lp *= ((lane >> 3) & 1) ? es[LW3] : ec[LW3];
  lp *= ((lane >> 4) & 1) ? es[LW4] : ec[LW4];
  lp *= ((lane >> 5) & 1) ? es[LW5] : ec[LW5];
  float re[16], im[16];
  #pragma unroll
  for (int sl = 0; sl < 16; ++sl) {
    float a = lp;
    a *= (sl & 1) ? es[RW0] : ec[RW0];
    a *= (sl & 2) ? es[RW1] : ec[RW1];
    a *= (sl & 4) ? es[RW2] : ec[RW2];
    a *= (sl & 8) ? es[RW3] : ec[RW3];
    re[sl] = a; im[sl] = 0.0f;
  }

  run_gates<0, SAFE>(re, im, tc, ts, u, cx);

  float hwv[N_WIRES];
  #pragma unroll
  for (int w = 0; w < N_WIRES; ++w) hwv[w] = hw[w];
  float lw = (((lane >> 0) & 1) ? -hwv[LW0] : hwv[LW0])
           + (((lane >> 1) & 1) ? -hwv[LW1] : hwv[LW1])
           + (((lane >> 2) & 1) ? -hwv[LW2] : hwv[LW2])
           + (((lane >> 3) & 1) ? -hwv[LW3] : hwv[LW3])
           + (((lane >> 4) & 1) ? -hwv[LW4] : hwv[LW4])
           + (((lane >> 5) & 1) ? -hwv[LW5] : hwv[LW5]);
  float acc = 0.0f;
  #pragma unroll
  for (int sl = 0; sl < 16; ++sl) {
    float sw = lw;
    sw += (sl & 1) ? -hwv[RW0] : hwv[RW0];
    sw += (sl & 2) ? -hwv[RW1] : hwv[RW1];
    sw += (sl & 4) ? -hwv[RW2] : hwv[RW2];
    sw += (sl & 8) ? -hwv[RW3] : hwv[RW3];
    acc += (re[sl] * re[sl] + im[sl] * im[sl]) * sw;
  }
  acc += xshfl<1,  SAFE>(acc, cx);
  acc += xshfl<2,  SAFE>(acc, cx);
  acc += xshfl<4,  SAFE>(acc, cx);
  acc += xshfl<8,  SAFE>(acc, cx);
  acc += xshfl<16, SAFE>(acc, cx);
  acc += xshfl<32, SAFE>(acc, cx);
  if (lane == 0) {
    const float logit = acc + hb[0] + 1.57079632679489662f;  // + SHIFT
    out[b] = 1.0f / (1.0f + expf(-logit));
  }
}

__global__ __launch_bounds__(256)
void qsim_kernel(const float* __restrict__ xb, const float* __restrict__ rxt,
                 const float* __restrict__ ryt, const float* __restrict__ rp,
                 const float* __restrict__ hw, const float* __restrict__ hb,
                 float* __restrict__ out, int bsz) {
  const int lane = threadIdx.x & 63;
  const int b = blockIdx.x * 4 + (threadIdx.x >> 6);  // one wave = one sample
  if (b >= bsz) return;

  // angle table: lanes 0..9 encoder, 10..39 rand, 40 rx, 41 ry
  float tc, ts;
  {
    float t = 0.0f;
    if (lane < 10)        t = xb[(size_t)b * 10 + lane];
    else if (lane < 40)   t = rp[lane - 10];
    else if (lane == 40)  t = rxt[0];
    else if (lane == 41)  t = ryt[0];
    float s, c;
    sincosf(0.5f * t, &s, &c);
    tc = c; ts = s;
  }

  // ---- mechanism self-test: orientation probes + end-to-end validation ----
  Ctx cx; cx.lane = lane; cx.f16 = false; cx.f32 = false;
#if __has_builtin(__builtin_amdgcn_permlane16_swap)
  {
    auto r = __builtin_amdgcn_permlane16_swap(lane, lane, false, false);
    cx.f16 = (((lane & 16) ? r[0] : r[1]) != (lane ^ 16));
  }
#endif
#if __has_builtin(__builtin_amdgcn_permlane32_swap)
  {
    auto r = __builtin_amdgcn_permlane32_swap(lane, lane, false, false);
    cx.f32 = (((lane & 32) ? r[0] : r[1]) != (lane ^ 32));
  }
#endif
  bool ok = true;
  ok &= (__float_as_int(xshfl<1,  false>(__int_as_float(lane), cx)) == (lane ^ 1));
  ok &= (__float_as_int(xshfl<2,  false>(__int_as_float(lane), cx)) == (lane ^ 2));
  ok &= (__float_as_int(xshfl<4,  false>(__int_as_float(lane), cx)) == (lane ^ 4));
  ok &= (__float_as_int(xshfl<8,  false>(__int_as_float(lane), cx)) == (lane ^ 8));
  ok &= (__float_as_int(xshfl<16, false>(__int_as_float(lane), cx)) == (lane ^ 16));
  ok &= (__float_as_int(xshfl<32, false>(__int_as_float(lane), cx)) == (lane ^ 32));
  const bool fast = (__all((int)ok) != 0);

  if (fast) body<false>(cx, b, tc, ts, hw, hb, out);
  else      body<true >(cx, b, tc, ts, hw, hb, out);
}

// ---------------------------------- launch -----------------------------------

extern "C" void kernel_launch(void* const* d_in, const int* in_sizes, int n_in,
                              void* d_out, int out_size, void* d_ws, size_t ws_size,
                              hipStream_t stream) {
  const float* xb  = (const float*)d_in[0];
  const float* rxt = (const float*)d_in[1];
  const float* ryt = (const float*)d_in[2];
  const float* rp  = (const float*)d_in[3];
  const float* hw  = (const float*)d_in[4];
  const float* hb  = (const float*)d_in[5];
  float* out = (float*)d_out;

  const int bsz = in_sizes[0] / N_WIRES;
  const int nblk = (bsz + 3) / 4;

  hipLaunchKernelGGL(qsim_kernel, dim3(nblk), dim3(256), 0, stream,
                     xb, rxt, ryt, rp, hw, hb, out, bsz);
}

// Round 6
// 27.622 us; speedup vs baseline: 3.0947x; 1.2084x over previous
//
#include <hip/hip_runtime.h>
#include <cstdint>
#include <cmath>

#define N_WIRES 10
#define N_OPS 30
#define NG_FAST 40   // 30 random + 10 fused(RY*RX)
#define NG_SAFE 50   // 30 random + 10x(RX,RY) separate (R3-proven tail)
#define NG_MAX 50

typedef __attribute__((ext_vector_type(2))) float f2;   // (re, im) packed pair

// ---------------- compile-time numpy RandomState(42) replication -------------

struct CERng { uint32_t mt[624]; int mti; };

constexpr uint32_t ce_next32(CERng& r) {
  if (r.mti >= 624) {
    for (int i = 0; i < 624; ++i) {
      uint32_t y = (r.mt[i] & 0x80000000u) | (r.mt[(i + 1) % 624] & 0x7fffffffu);
      uint32_t v = r.mt[(i + 397) % 624] ^ (y >> 1);
      if (y & 1u) v ^= 2567483615u;
      r.mt[i] = v;
    }
    r.mti = 0;
  }
  uint32_t y = r.mt[r.mti++];
  y ^= y >> 11;
  y ^= (y << 7) & 2636928640u;
  y ^= (y << 15) & 4022730752u;
  y ^= y >> 18;
  return y;
}

constexpr uint32_t ce_masked(CERng& r, uint32_t rng) {  // legacy single-32b draw (R2-validated)
  if (rng == 0) return 0;
  uint32_t mask = rng;
  mask |= mask >> 1; mask |= mask >> 2; mask |= mask >> 4;
  mask |= mask >> 8; mask |= mask >> 16;
  uint32_t v = ce_next32(r) & mask;
  while (v > rng) v = ce_next32(r) & mask;
  return v;
}

// type: 0=rx 1=ry 2=rz 3=cnot 4=fused(RY*RX).  p0/p1 are BIT positions after remap.
struct Full { int n; int type[NG_MAX]; int p0[NG_MAX]; int p1[NG_MAX]; int aidx[NG_MAX]; int wbit[N_WIRES]; };

constexpr Full make_full(bool fused) {
  Full f{};
  int rty[N_OPS] = {}, rw0[N_OPS] = {}, rw1[N_OPS] = {};
  CERng r{};
  r.mt[0] = 42u;
  for (int i = 1; i < 624; ++i)
    r.mt[i] = 1812433253u * (r.mt[i - 1] ^ (r.mt[i - 1] >> 30)) + (uint32_t)i;
  r.mti = 624;
  for (int k = 0; k < N_OPS; ++k) {
    int g = (int)ce_masked(r, 3u);
    if (g == 3) {
      int arr[N_WIRES] = {0,1,2,3,4,5,6,7,8,9};
      for (int i = N_WIRES - 1; i >= 1; --i) {
        int j = (int)ce_masked(r, (uint32_t)i);
        int t = arr[i]; arr[i] = arr[j]; arr[j] = t;
      }
      rty[k] = 3; rw0[k] = arr[0]; rw1[k] = arr[1];
    } else {
      rty[k] = g; rw0[k] = (int)ce_masked(r, 9u); rw1[k] = -1;
    }
  }
  int cost[N_WIRES] = {};
  for (int k = 0; k < N_OPS; ++k) {
    if (rty[k] == 3) { cost[rw0[k]] += 1; cost[rw1[k]] += 2; }
    else if (rty[k] != 2) cost[rw0[k]] += 2;
  }
  for (int w = 0; w < N_WIRES; ++w) cost[w] += 2;
  int ord[N_WIRES] = {0,1,2,3,4,5,6,7,8,9};
  for (int i = 0; i < N_WIRES; ++i) {
    int best = i;
    for (int j = i + 1; j < N_WIRES; ++j)
      if (cost[ord[j]] > cost[ord[best]]) best = j;
    int t = ord[i]; ord[i] = ord[best]; ord[best] = t;
  }
  // hottest 4 -> register bits; lane bits: bit4/5=DPP(mask1/2), bit8/9=permlane(16/32), bit6/7=ds_swizzle(4/8)
  f.wbit[ord[0]] = 3; f.wbit[ord[1]] = 2; f.wbit[ord[2]] = 1; f.wbit[ord[3]] = 0;
  f.wbit[ord[4]] = 4; f.wbit[ord[5]] = 5;
  f.wbit[ord[6]] = 8; f.wbit[ord[7]] = 9;
  f.wbit[ord[8]] = 6; f.wbit[ord[9]] = 7;
  for (int k = 0; k < N_OPS; ++k) {
    f.type[k] = rty[k];
    if (rty[k] == 3) { f.p0[k] = f.wbit[rw0[k]]; f.p1[k] = f.wbit[rw1[k]]; f.aidx[k] = 0; }
    else             { f.p0[k] = f.wbit[rw0[k]]; f.p1[k] = 0; f.aidx[k] = 10 + k; }
  }
  if (fused) {
    f.n = NG_FAST;
    for (int w = 0; w < N_WIRES; ++w) {
      f.type[N_OPS + w] = 4; f.p0[N_OPS + w] = f.wbit[w]; f.p1[N_OPS + w] = 0; f.aidx[N_OPS + w] = 0;
    }
  } else {
    f.n = NG_SAFE;
    for (int w = 0; w < N_WIRES; ++w) {
      f.type[N_OPS + 2*w]     = 0; f.p0[N_OPS + 2*w]     = f.wbit[w]; f.p1[N_OPS + 2*w]     = 0; f.aidx[N_OPS + 2*w]     = 40;
      f.type[N_OPS + 2*w + 1] = 1; f.p0[N_OPS + 2*w + 1] = f.wbit[w]; f.p1[N_OPS + 2*w + 1] = 0; f.aidx[N_OPS + 2*w + 1] = 41;
    }
  }
  return f;
}

constexpr Full FULLF = make_full(true);
constexpr Full FULLS = make_full(false);

constexpr int wire_at_bit(int bp) {
  for (int w = 0; w < N_WIRES; ++w) if (FULLF.wbit[w] == bp) return w;
  return 0;
}
constexpr int RW0 = wire_at_bit(0), RW1 = wire_at_bit(1), RW2 = wire_at_bit(2), RW3 = wire_at_bit(3);
constexpr int LW0 = wire_at_bit(4), LW1 = wire_at_bit(5), LW2 = wire_at_bit(6),
              LW3 = wire_at_bit(7), LW4 = wire_at_bit(8), LW5 = wire_at_bit(9);

// --------------------------------- device ------------------------------------

struct U2v { f2 u00, u01, u10, u11; };   // complex entries as (re, im)
struct Ctx { int lane; bool f16, f32; };

__device__ inline f2 fswap(f2 v) { return __builtin_shufflevector(v, v, 1, 0); }

// complex multiply-accumulate: acc + u*a  (u, a complex as f2)
__device__ inline f2 cmad(f2 u, f2 a, f2 acc) {
  const f2 un = {-u.y, u.y};
  return acc + u.x * a + un * fswap(a);
}

template <bool SAFE>
__device__ inline float bcast(float x, int l) {
  if constexpr (SAFE) return __shfl(x, l, 64);
  else return __int_as_float(__builtin_amdgcn_readlane(__float_as_int(x), l));
}

// xor-exchange across lanes (R5-proven mechanism layer; SAFE => __shfl_xor)
template <int MASK, bool SAFE>
__device__ inline float xshfl(float x, const Ctx& cx) {
  if constexpr (SAFE) {
    return __shfl_xor(x, MASK, 64);
  } else if constexpr (MASK == 1) {
    return __int_as_float(__builtin_amdgcn_update_dpp(0, __float_as_int(x), 0xB1, 0xF, 0xF, true));
  } else if constexpr (MASK == 2) {
    return __int_as_float(__builtin_amdgcn_update_dpp(0, __float_as_int(x), 0x4E, 0xF, 0xF, true));
  } else if constexpr (MASK == 4 || MASK == 8) {
    return __int_as_float(__builtin_amdgcn_ds_swizzle(__float_as_int(x), (MASK << 10) | 0x1F));
  } else if constexpr (MASK == 16) {
#if __has_builtin(__builtin_amdgcn_permlane16_swap)
    auto r = __builtin_amdgcn_permlane16_swap(__float_as_int(x), __float_as_int(x), false, false);
    const int a = (cx.lane & 16) ? r[0] : r[1];
    const int b = (cx.lane & 16) ? r[1] : r[0];
    return __int_as_float(cx.f16 ? b : a);
#else
    return __shfl_xor(x, 16, 64);
#endif
  } else {
#if __has_builtin(__builtin_amdgcn_permlane32_swap)
    auto r = __builtin_amdgcn_permlane32_swap(__float_as_int(x), __float_as_int(x), false, false);
    const int a = (cx.lane & 32) ? r[0] : r[1];
    const int b = (cx.lane & 32) ? r[1] : r[0];
    return __int_as_float(cx.f32 ? b : a);
#else
    return __shfl_xor(x, 32, 64);
#endif
  }
}

template <int MASK, bool SAFE>
__device__ inline f2 xshfl2(f2 v, const Ctx& cx) {
  f2 r;
  r.x = xshfl<MASK, SAFE>(v.x, cx);
  r.y = xshfl<MASK, SAFE>(v.y, cx);
  return r;
}

template <int TY, int P>
__device__ inline void gate_local(f2 (&st)[16], float c, float s) {
  const f2 c2 = {c, c}, s2 = {s, s}, sn = {s, -s};
  #pragma unroll
  for (int b = 0; b < 16; ++b) {
    if ((b >> P) & 1) continue;
    const int i0 = b, i1 = b | (1 << P);
    const f2 a0 = st[i0], a1 = st[i1];
    if constexpr (TY == 0) {              // RX: a' = c*a + (s,-s)*swap(partner)
      st[i0] = c2 * a0 + sn * fswap(a1);
      st[i1] = c2 * a1 + sn * fswap(a0);
    } else if constexpr (TY == 1) {       // RY: componentwise
      st[i0] = c2 * a0 - s2 * a1;
      st[i1] = c2 * a1 + s2 * a0;
    } else {                              // RZ: diagonal
      st[i0] = c2 * a0 + sn * fswap(a0);
      st[i1] = c2 * a1 - sn * fswap(a1);
    }
  }
}

template <int TY, int LB, bool SAFE>
__device__ inline void gate_lane(f2 (&st)[16], float c, float s, const Ctx& cx) {
  const f2 c2 = {c, c};
  if constexpr (TY == 2) {                // RZ: diagonal, no exchange
    const float t = ((cx.lane >> LB) & 1) ? -s : s;
    const f2 tn = {t, -t};
    #pragma unroll
    for (int j = 0; j < 16; ++j) st[j] = c2 * st[j] + tn * fswap(st[j]);
  } else if constexpr (TY == 0) {         // RX
    const f2 sn = {s, -s};
    #pragma unroll
    for (int j = 0; j < 16; ++j) {
      const f2 p = xshfl2<(1 << LB), SAFE>(st[j], cx);
      st[j] = c2 * st[j] + sn * fswap(p);
    }
  } else {                                // RY
    const float sg = ((cx.lane >> LB) & 1) ? s : -s;
    const f2 sg2 = {sg, sg};
    #pragma unroll
    for (int j = 0; j < 16; ++j) {
      const f2 p = xshfl2<(1 << LB), SAFE>(st[j], cx);
      st[j] = c2 * st[j] + sg2 * p;
    }
  }
}

template <int P>
__device__ inline void fused_local(f2 (&st)[16], const U2v& u) {
  #pragma unroll
  for (int b = 0; b < 16; ++b) {
    if ((b >> P) & 1) continue;
    const int i0 = b, i1 = b | (1 << P);
    const f2 a0 = st[i0], a1 = st[i1];
    st[i0] = cmad(u.u01, a1, cmad(u.u00, a0, (f2){0.f, 0.f}));
    st[i1] = cmad(u.u11, a1, cmad(u.u10, a0, (f2){0.f, 0.f}));
  }
}

template <int LB, bool SAFE>
__device__ inline void fused_lane(f2 (&st)[16], const U2v& u, const Ctx& cx) {
  const bool hi = (cx.lane >> LB) & 1;
  const f2 A = hi ? u.u11 : u.u00;
  const f2 B = hi ? u.u10 : u.u01;
  #pragma unroll
  for (int j = 0; j < 16; ++j) {
    const f2 p = xshfl2<(1 << LB), SAFE>(st[j], cx);
    st[j] = cmad(B, p, cmad(A, st[j], (f2){0.f, 0.f}));
  }
}

template <int CB, int TB, bool SAFE>
__device__ inline void cnot_gate(f2 (&st)[16], const Ctx& cx) {
  if constexpr (CB < 4 && TB < 4) {
    #pragma unroll
    for (int b = 0; b < 16; ++b) {
      if (((b >> CB) & 1) && !((b >> TB) & 1)) {
        const int j = b | (1 << TB);
        const f2 t = st[b]; st[b] = st[j]; st[j] = t;
      }
    }
  } else if constexpr (CB < 4) {
    constexpr int M = 1 << (TB - 4);
    #pragma unroll
    for (int b = 0; b < 16; ++b) {
      if ((b >> CB) & 1) st[b] = xshfl2<M, SAFE>(st[b], cx);
    }
  } else if constexpr (TB < 4) {
    const bool cb = (cx.lane >> (CB - 4)) & 1;
    #pragma unroll
    for (int b = 0; b < 16; ++b) {
      if (!((b >> TB) & 1)) {
        const int j = b | (1 << TB);
        const f2 a0 = st[b], a1 = st[j];
        st[b] = cb ? a1 : a0; st[j] = cb ? a0 : a1;
      }
    }
  } else {
    const bool cb = (cx.lane >> (CB - 4)) & 1;
    constexpr int M = 1 << (TB - 4);
    #pragma unroll
    for (int j = 0; j < 16; ++j) {
      const f2 p = xshfl2<M, SAFE>(st[j], cx);
      st[j] = cb ? p : st[j];
    }
  }
}

template <int K, bool SAFE>
__device__ inline void run_gates(f2 (&st)[16], float tc, float ts, const U2v& u, const Ctx& cx) {
  constexpr int NG = SAFE ? NG_SAFE : NG_FAST;
  if constexpr (K < NG) {
    constexpr int ty = SAFE ? FULLS.type[K] : FULLF.type[K];
    constexpr int P0 = SAFE ? FULLS.p0[K]   : FULLF.p0[K];
    constexpr int P1 = SAFE ? FULLS.p1[K]   : FULLF.p1[K];
    constexpr int AI = SAFE ? FULLS.aidx[K] : FULLF.aidx[K];
    if constexpr (ty == 3) {
      cnot_gate<P0, P1, SAFE>(st, cx);
    } else if constexpr (ty == 4) {
      if constexpr (P0 < 4) fused_local<P0>(st, u);
      else                  fused_lane<P0 - 4, SAFE>(st, u, cx);
    } else {
      const float c = bcast<SAFE>(tc, AI);
      const float s = bcast<SAFE>(ts, AI);
      if constexpr (P0 < 4) gate_local<ty, P0>(st, c, s);
      else                  gate_lane<ty, P0 - 4, SAFE>(st, c, s, cx);
    }
    run_gates<K + 1, SAFE>(st, tc, ts, u, cx);
  }
}

template <bool SAFE>
__device__ inline void body(const Ctx& cx, int b, float tc, float ts,
                            const float* __restrict__ hw, const float* __restrict__ hb,
                            float* __restrict__ out) {
  const int lane = cx.lane;
  U2v u;
  {
    const float cxr = bcast<SAFE>(tc, 40), sxr = bcast<SAFE>(ts, 40);
    const float cyr = bcast<SAFE>(tc, 41), syr = bcast<SAFE>(ts, 41);
    u.u00 = (f2){ cyr * cxr,  syr * sxr};
    u.u01 = (f2){-syr * cxr, -cyr * sxr};
    u.u10 = (f2){ syr * cxr, -cyr * sxr};
    u.u11 = (f2){ cyr * cxr, -syr * sxr};
  }
  float ec[N_WIRES], es[N_WIRES];
  #pragma unroll
  for (int w = 0; w < N_WIRES; ++w) { ec[w] = bcast<SAFE>(tc, w); es[w] = bcast<SAFE>(ts, w); }

  float lp = ((lane >> 0) & 1) ? es[LW0] : ec[LW0];
  lp *= ((lane >> 1) & 1) ? es[LW1] : ec[LW1];
  lp *= ((lane >> 2) & 1) ? es[LW2] : ec[LW2];
  lp *= ((lane >> 3) & 1) ? es[LW3] : ec[LW3];
  lp *= ((lane >> 4) & 1) ? es[LW4] : ec[LW4];
  lp *= ((lane >> 5) & 1) ? es[LW5] : ec[LW5];
  f2 st[16];
  #pragma unroll
  for (int sl = 0; sl < 16; ++sl) {
    float a = lp;
    a *= (sl & 1) ? es[RW0] : ec[RW0];
    a *= (sl & 2) ? es[RW1] : ec[RW1];
    a *= (sl & 4) ? es[RW2] : ec[RW2];
    a *= (sl & 8) ? es[RW3] : ec[RW3];
    st[sl] = (f2){a, 0.0f};
  }

  run_gates<0, SAFE>(st, tc, ts, u, cx);

  float hwv[N_WIRES];
  #pragma unroll
  for (int w = 0; w < N_WIRES; ++w) hwv[w] = hw[w];
  float lw = (((lane >> 0) & 1) ? -hwv[LW0] : hwv[LW0])
           + (((lane >> 1) & 1) ? -hwv[LW1] : hwv[LW1])
           + (((lane >> 2) & 1) ? -hwv[LW2] : hwv[LW2])
           + (((lane >> 3) & 1) ? -hwv[LW3] : hwv[LW3])
           + (((lane >> 4) & 1) ? -hwv[LW4] : hwv[LW4])
           + (((lane >> 5) & 1) ? -hwv[LW5] : hwv[LW5]);
  float acc = 0.0f;
  #pragma unroll
  for (int sl = 0; sl < 16; ++sl) {
    float sw = lw;
    sw += (sl & 1) ? -hwv[RW0] : hwv[RW0];
    sw += (sl & 2) ? -hwv[RW1] : hwv[RW1];
    sw += (sl & 4) ? -hwv[RW2] : hwv[RW2];
    sw += (sl & 8) ? -hwv[RW3] : hwv[RW3];
    const f2 q = st[sl] * st[sl];
    acc += (q.x + q.y) * sw;
  }
  acc += xshfl<1,  SAFE>(acc, cx);
  acc += xshfl<2,  SAFE>(acc, cx);
  acc += xshfl<4,  SAFE>(acc, cx);
  acc += xshfl<8,  SAFE>(acc, cx);
  acc += xshfl<16, SAFE>(acc, cx);
  acc += xshfl<32, SAFE>(acc, cx);
  if (lane == 0) {
    const float logit = acc + hb[0] + 1.57079632679489662f;  // + SHIFT
    out[b] = 1.0f / (1.0f + expf(-logit));
  }
}

__global__ __launch_bounds__(256)
void qsim_kernel(const float* __restrict__ xb, const float* __restrict__ rxt,
                 const float* __restrict__ ryt, const float* __restrict__ rp,
                 const float* __restrict__ hw, const float* __restrict__ hb,
                 float* __restrict__ out, int bsz) {
  const int lane = threadIdx.x & 63;
  const int b = blockIdx.x * 4 + (threadIdx.x >> 6);  // one wave = one sample
  if (b >= bsz) return;

  float tc, ts;
  {
    float t = 0.0f;
    if (lane < 10)        t = xb[(size_t)b * 10 + lane];
    else if (lane < 40)   t = rp[lane - 10];
    else if (lane == 40)  t = rxt[0];
    else if (lane == 41)  t = ryt[0];
    float s, c;
    sincosf(0.5f * t, &s, &c);
    tc = c; ts = s;
  }

  // ---- mechanism self-test (R5-proven): orientation probes + end-to-end ----
  Ctx cx; cx.lane = lane; cx.f16 = false; cx.f32 = false;
#if __has_builtin(__builtin_amdgcn_permlane16_swap)
  {
    auto r = __builtin_amdgcn_permlane16_swap(lane, lane, false, false);
    cx.f16 = (((lane & 16) ? r[0] : r[1]) != (lane ^ 16));
  }
#endif
#if __has_builtin(__builtin_amdgcn_permlane32_swap)
  {
    auto r = __builtin_amdgcn_permlane32_swap(lane, lane, false, false);
    cx.f32 = (((lane & 32) ? r[0] : r[1]) != (lane ^ 32));
  }
#endif
  bool ok = true;
  ok &= (__float_as_int(xshfl<1,  false>(__int_as_float(lane), cx)) == (lane ^ 1));
  ok &= (__float_as_int(xshfl<2,  false>(__int_as_float(lane), cx)) == (lane ^ 2));
  ok &= (__float_as_int(xshfl<4,  false>(__int_as_float(lane), cx)) == (lane ^ 4));
  ok &= (__float_as_int(xshfl<8,  false>(__int_as_float(lane), cx)) == (lane ^ 8));
  ok &= (__float_as_int(xshfl<16, false>(__int_as_float(lane), cx)) == (lane ^ 16));
  ok &= (__float_as_int(xshfl<32, false>(__int_as_float(lane), cx)) == (lane ^ 32));
  const bool fast = (__all((int)ok) != 0);

  if (fast) body<false>(cx, b, tc, ts, hw, hb, out);
  else      body<true >(cx, b, tc, ts, hw, hb, out);
}

// ---------------------------------- launch -----------------------------------

extern "C" void kernel_launch(void* const* d_in, const int* in_sizes, int n_in,
                              void* d_out, int out_size, void* d_ws, size_t ws_size,
                              hipStream_t stream) {
  const float* xb  = (const float*)d_in[0];
  const float* rxt = (const float*)d_in[1];
  const float* ryt = (const float*)d_in[2];
  const float* rp  = (const float*)d_in[3];
  const float* hw  = (const float*)d_in[4];
  const float* hb  = (const float*)d_in[5];
  float* out = (float*)d_out;

  const int bsz = in_sizes[0] / N_WIRES;
  const int nblk = (bsz + 3) / 4;

  hipLaunchKernelGGL(qsim_kernel, dim3(nblk), dim3(256), 0, stream,
                     xb, rxt, ryt, rp, hw, hb, out, bsz);
}